// Round 2
// baseline (371.290 us; speedup 1.0000x reference)
//
#include <hip/hip_runtime.h>
#include <math.h>

// Problem constants
// B=8, NC=32, N=128, D_N=64, ALPHA=4, HS=128, HM=128, HMOD=64
// MOD_IN=133, MOD_OUT=16512

// Output offsets (floats) in d_out (concatenated return tuple)
#define OUT_RO   0u
#define OUT_H    16384u
#define OUT_MSG  2113536u
#define OUT_W    4210688u
#define OUT_DEC  8404992u

#define TID ((int)threadIdx.x)

__device__ __forceinline__ float tanh_f(float v){ return tanhf(v); }

// ---------------------------------------------------------------------------
// Kernel 1: one block per (b,c) cell. Full matmul chain in LDS.
// ---------------------------------------------------------------------------
__global__ __launch_bounds__(256, 1)
void k1_cell(const float* __restrict__ x,
             const float* __restrict__ hg,
             const float* __restrict__ msgg,
             const float* __restrict__ Wg,
             const float* __restrict__ decay_logit,
             const float* __restrict__ readout_drift,
             const float* __restrict__ s_mem_live,
             const float* __restrict__ s_mem_ema_fast,
             const float* __restrict__ neuron_id,
             const float* __restrict__ state_w1,
             const float* __restrict__ state_b1,
             const float* __restrict__ state_w2,
             const float* __restrict__ state_b2,
             const float* __restrict__ msg_w1,
             const float* __restrict__ msg_b1,
             const float* __restrict__ msg_w2,
             const float* __restrict__ msg_b2,
             const float* __restrict__ inject_w,
             const float* __restrict__ inject_b,
             const float* __restrict__ mod_w1,
             const float* __restrict__ mod_b1,
             float* __restrict__ out,
             float* __restrict__ hid_ws)
{
    // LDS: D = 128x132 (W -> state_w1 -> hidden -> mh)
    //      A = 128x68  (msg -> received -> w2^T -> msg_w1 -> msg_w2^T)
    //      B = 128x68  (h -> h_new -> msg_new)
    __shared__ __align__(16) float sD[128*132];
    __shared__ __align__(16) float sA[128*68];
    __shared__ __align__(16) float sB[128*68];
    __shared__ __align__(16) float s_b1[128];
    __shared__ __align__(16) float s_mb1[128];
    __shared__ __align__(16) float s_b2[64];
    __shared__ __align__(16) float s_mb2[64];
    __shared__ __align__(16) float s_cell[64];
    __shared__ __align__(16) float s_dlog[128];
    __shared__ __align__(16) float s_dec[128];
    __shared__ __align__(16) float s_modin[136];
    __shared__ __align__(16) float s_scr[16*68];
    __shared__ float s_wpart[4];

    const int bid = blockIdx.x;          // b*32 + c
    const int b   = bid >> 5;
    const int c   = bid & 31;
    const int ty  = TID >> 4;            // 0..15
    const int tx  = TID & 15;            // 0..15
    const int d4  = tx * 4;

    // ---------------- Phase 1: loads ----------------
    float wabs = 0.f;
    {
        const float4* src = (const float4*)(Wg + (size_t)bid * 16384);
        #pragma unroll
        for (int it = 0; it < 16; ++it) {
            int f4i = TID + it * 256;            // float4 index into 128x128
            float4 v = src[f4i];
            int n = f4i >> 5, k = (f4i & 31) << 2;
            *(float4*)&sD[n*132 + k] = v;
            wabs += fabsf(v.x) + fabsf(v.y) + fabsf(v.z) + fabsf(v.w);
        }
    }
    {
        const float4* src = (const float4*)(msgg + (size_t)bid * 8192);
        #pragma unroll
        for (int it = 0; it < 8; ++it) {
            int f4i = TID + it * 256;            // into 128x64
            float4 v = src[f4i];
            int n = f4i >> 4, d = (f4i & 15) << 2;
            *(float4*)&sA[n*68 + d] = v;
        }
    }
    {
        const float4* src = (const float4*)(hg + (size_t)bid * 8192);
        #pragma unroll
        for (int it = 0; it < 8; ++it) {
            int f4i = TID + it * 256;
            float4 v = src[f4i];
            int n = f4i >> 4, d = (f4i & 15) << 2;
            *(float4*)&sB[n*68 + d] = v;
        }
    }
    if (TID < 128) {
        s_b1[TID]  = state_b1[TID];
        s_mb1[TID] = msg_b1[TID];
        float dl = decay_logit[(size_t)bid*128 + TID];
        s_dlog[TID] = dl;
        s_dec[TID]  = 1.f / (1.f + expf(-dl));
    }
    if (TID < 64) {
        s_b2[TID]   = state_b2[TID];
        s_mb2[TID]  = msg_b2[TID];
        s_cell[TID] = x[(size_t)b*2048 + c*64 + TID];
    }
    // |W| wave reduction
    #pragma unroll
    for (int off = 32; off > 0; off >>= 1) wabs += __shfl_down(wabs, off);
    if ((TID & 63) == 0) s_wpart[TID >> 6] = wabs;

    __syncthreads();   // (1)

    // ---------------- Phase 2: received = W @ msg ----------------
    float4 acc[8];
    #pragma unroll
    for (int i = 0; i < 8; ++i) acc[i] = make_float4(0.f,0.f,0.f,0.f);
    #pragma unroll 4
    for (int k = 0; k < 128; ++k) {
        float4 m4 = *(const float4*)&sA[k*68 + d4];
        #pragma unroll
        for (int i = 0; i < 8; ++i) {
            float w = sD[(ty + 16*i)*132 + k];
            acc[i].x += w * m4.x; acc[i].y += w * m4.y;
            acc[i].z += w * m4.z; acc[i].w += w * m4.w;
        }
    }
    __syncthreads();   // all reads of msg (sA) and W (sD) done

    // store received -> sA; load state_w1 -> sD; thread0: modin tail
    #pragma unroll
    for (int i = 0; i < 8; ++i)
        *(float4*)&sA[(ty + 16*i)*68 + d4] = acc[i];
    {
        const float4* src = (const float4*)state_w1;
        #pragma unroll
        for (int it = 0; it < 16; ++it) {
            int f4i = TID + it * 256;
            float4 v = src[f4i];
            int n = f4i >> 5, k = (f4i & 31) << 2;
            *(float4*)&sD[n*132 + k] = v;
        }
    }
    if (TID == 0) {
        float ws_ = (s_wpart[0] + s_wpart[1] + s_wpart[2] + s_wpart[3]) * (1.f/16384.f);
        float ds = 0.f;
        for (int n = 0; n < 128; ++n) ds += s_dlog[n];
        s_modin[128] = ws_;
        s_modin[129] = ds * (1.f/128.f);
        s_modin[130] = readout_drift[bid];
        s_modin[131] = s_mem_live[b];
        s_modin[132] = s_mem_ema_fast[b];
    }
    __syncthreads();   // received visible

    // inject: received[0:4][:] += cell @ inject_w[c]^T + inject_b[c]
    {
        int o = TID;                               // 0..255
        float s = inject_b[(size_t)c*256 + o];
        const float4* iw = (const float4*)(inject_w + (size_t)c*16384 + (size_t)o*64);
        #pragma unroll 4
        for (int q = 0; q < 16; ++q) {
            float4 w4 = iw[q];
            float4 cl = *(const float4*)&s_cell[q*4];
            s += w4.x*cl.x + w4.y*cl.y + w4.z*cl.z + w4.w*cl.w;
        }
        sA[(o >> 6)*68 + (o & 63)] += s;
    }
    __syncthreads();

    // ---------------- Phase 3: hidden = tanh(recv@w1r^T + h@w1h^T + b1) ----
    {
        float acc2[8][8];
        #pragma unroll
        for (int i = 0; i < 8; ++i)
            #pragma unroll
            for (int j = 0; j < 8; ++j) acc2[i][j] = 0.f;
        #pragma unroll 2
        for (int k = 0; k < 64; ++k) {
            float rv[8], hv[8], wr[8], wh[8];
            #pragma unroll
            for (int i = 0; i < 8; ++i) {
                int n = ty + 16*i;
                rv[i] = sA[n*68 + k];
                hv[i] = sB[n*68 + k];
            }
            #pragma unroll
            for (int j = 0; j < 8; ++j) {
                int hh = tx + 16*j;
                wr[j] = sD[hh*132 + k];
                wh[j] = sD[hh*132 + 64 + k];
            }
            #pragma unroll
            for (int i = 0; i < 8; ++i)
                #pragma unroll
                for (int j = 0; j < 8; ++j)
                    acc2[i][j] += rv[i]*wr[j] + hv[i]*wh[j];
        }
        __syncthreads();   // reads of state_w1(sD)/received(sA) done
        // hidden -> sD ; state_w2^T -> sA
        #pragma unroll
        for (int i = 0; i < 8; ++i)
            #pragma unroll
            for (int j = 0; j < 8; ++j)
                sD[(ty + 16*i)*132 + (tx + 16*j)] = tanh_f(acc2[i][j] + s_b1[tx + 16*j]);
    }
    {
        const float4* src = (const float4*)state_w2;   // (64,128)
        #pragma unroll
        for (int it = 0; it < 8; ++it) {
            int f4i = TID + it * 256;
            float4 v = src[f4i];
            int d = f4i >> 5, hh = (f4i & 31) << 2;
            sA[(hh+0)*68 + d] = v.x;
            sA[(hh+1)*68 + d] = v.y;
            sA[(hh+2)*68 + d] = v.z;
            sA[(hh+3)*68 + d] = v.w;
        }
    }
    __syncthreads();

    // ---------------- Phase 4: cand -> h_new -------------------------------
    {
        #pragma unroll
        for (int i = 0; i < 8; ++i) acc[i] = make_float4(0.f,0.f,0.f,0.f);
        #pragma unroll 4
        for (int k = 0; k < 128; ++k) {          // k = hh
            float4 w4 = *(const float4*)&sA[k*68 + d4];
            #pragma unroll
            for (int i = 0; i < 8; ++i) {
                float hv = sD[(ty + 16*i)*132 + k];
                acc[i].x += hv * w4.x; acc[i].y += hv * w4.y;
                acc[i].z += hv * w4.z; acc[i].w += hv * w4.w;
            }
        }
        float4 b2v = *(const float4*)&s_b2[d4];
        float4 hpart = make_float4(0.f,0.f,0.f,0.f);
        #pragma unroll
        for (int i = 0; i < 8; ++i) {
            int n = ty + 16*i;
            float dec = s_dec[n];
            float4 hold = *(const float4*)&sB[n*68 + d4];
            float4 hn;
            hn.x = dec*hold.x + (1.f-dec)*tanh_f(acc[i].x + b2v.x);
            hn.y = dec*hold.y + (1.f-dec)*tanh_f(acc[i].y + b2v.y);
            hn.z = dec*hold.z + (1.f-dec)*tanh_f(acc[i].z + b2v.z);
            hn.w = dec*hold.w + (1.f-dec)*tanh_f(acc[i].w + b2v.w);
            *(float4*)&sB[n*68 + d4] = hn;
            *(float4*)(out + OUT_H + (size_t)bid*8192 + n*64 + d4) = hn;
            hpart.x += hn.x; hpart.y += hn.y; hpart.z += hn.z; hpart.w += hn.w;
        }
        *(float4*)&s_scr[ty*68 + d4] = hpart;
    }
    __syncthreads();
    // finalize h_mean; load msg_w1 -> sA
    if (TID < 64) {
        float s = 0.f;
        #pragma unroll
        for (int t = 0; t < 16; ++t) s += s_scr[t*68 + TID];
        s_modin[TID] = s * (1.f/128.f);
    }
    {
        const float4* src = (const float4*)msg_w1;     // (128,64)
        #pragma unroll
        for (int it = 0; it < 8; ++it) {
            int f4i = TID + it * 256;
            float4 v = src[f4i];
            int hh = f4i >> 4, d = (f4i & 15) << 2;
            *(float4*)&sA[hh*68 + d] = v;
        }
    }
    __syncthreads();

    // ---------------- Phase 5: mh = tanh(h_new @ msg_w1^T + mb1) -----------
    {
        float acc2[8][8];
        #pragma unroll
        for (int i = 0; i < 8; ++i)
            #pragma unroll
            for (int j = 0; j < 8; ++j) acc2[i][j] = 0.f;
        #pragma unroll 2
        for (int k = 0; k < 64; ++k) {
            float hv[8], wv[8];
            #pragma unroll
            for (int i = 0; i < 8; ++i) hv[i] = sB[(ty + 16*i)*68 + k];
            #pragma unroll
            for (int j = 0; j < 8; ++j) wv[j] = sA[(tx + 16*j)*68 + k];
            #pragma unroll
            for (int i = 0; i < 8; ++i)
                #pragma unroll
                for (int j = 0; j < 8; ++j)
                    acc2[i][j] += hv[i]*wv[j];
        }
        __syncthreads();
        #pragma unroll
        for (int i = 0; i < 8; ++i)
            #pragma unroll
            for (int j = 0; j < 8; ++j)
                sD[(ty + 16*i)*132 + (tx + 16*j)] = tanh_f(acc2[i][j] + s_mb1[tx + 16*j]);
    }
    {
        const float4* src = (const float4*)msg_w2;     // (64,128) -> transpose
        #pragma unroll
        for (int it = 0; it < 8; ++it) {
            int f4i = TID + it * 256;
            float4 v = src[f4i];
            int d = f4i >> 5, hh = (f4i & 31) << 2;
            sA[(hh+0)*68 + d] = v.x;
            sA[(hh+1)*68 + d] = v.y;
            sA[(hh+2)*68 + d] = v.z;
            sA[(hh+3)*68 + d] = v.w;
        }
    }
    __syncthreads();

    // ---------------- Phase 6: msg_new --------------------------------------
    {
        #pragma unroll
        for (int i = 0; i < 8; ++i) acc[i] = make_float4(0.f,0.f,0.f,0.f);
        #pragma unroll 4
        for (int k = 0; k < 128; ++k) {          // k = hh
            float4 w4 = *(const float4*)&sA[k*68 + d4];
            #pragma unroll
            for (int i = 0; i < 8; ++i) {
                float mv = sD[(ty + 16*i)*132 + k];
                acc[i].x += mv * w4.x; acc[i].y += mv * w4.y;
                acc[i].z += mv * w4.z; acc[i].w += mv * w4.w;
            }
        }
        float4 mb2 = *(const float4*)&s_mb2[d4];
        float4 mpart = make_float4(0.f,0.f,0.f,0.f);
        #pragma unroll
        for (int i = 0; i < 8; ++i) {
            int n = ty + 16*i;
            float4 nid = *(const float4*)(neuron_id + (size_t)c*8192 + n*64 + d4);
            float4 mn;
            mn.x = tanh_f(acc[i].x + mb2.x) + nid.x;
            mn.y = tanh_f(acc[i].y + mb2.y) + nid.y;
            mn.z = tanh_f(acc[i].z + mb2.z) + nid.z;
            mn.w = tanh_f(acc[i].w + mb2.w) + nid.w;
            *(float4*)&sB[n*68 + d4] = mn;
            *(float4*)(out + OUT_MSG + (size_t)bid*8192 + n*64 + d4) = mn;
            mpart.x += mn.x; mpart.y += mn.y; mpart.z += mn.z; mpart.w += mn.w;
        }
        *(float4*)&s_scr[ty*68 + d4] = mpart;
    }
    __syncthreads();
    if (TID < 64) {
        float s = 0.f;
        #pragma unroll
        for (int t = 0; t < 16; ++t) s += s_scr[t*68 + TID];
        s_modin[64 + TID] = s * (1.f/128.f);
        // readout: rows 4..7 of msg_new, * ALPHA^-0.5 = 0.5
        float r = (sB[4*68 + TID] + sB[5*68 + TID] + sB[6*68 + TID] + sB[7*68 + TID]) * 0.5f;
        out[OUT_RO + (size_t)b*2048 + c*64 + TID] = r;
    }
    __syncthreads();

    // ---------------- Phase 7: hid = tanh(mod_input @ mod_w1[c] + mod_b1) --
    if (TID < 64) {
        int hh = TID;
        float a = mod_b1[(size_t)c*64 + hh];
        const float* w1p = mod_w1 + (size_t)c*8512 + hh;   // 133*64
        #pragma unroll 7
        for (int i = 0; i < 133; ++i)
            a += s_modin[i] * w1p[(size_t)i*64];
        hid_ws[(size_t)bid*64 + hh] = tanh_f(a);
    }
}

// ---------------------------------------------------------------------------
// Kernel 2: outm = hid @ mod_w2 + mod_b2; W_new, decay_new.
// Grid: 256 blocks = (c, part) pairs; each block: 2064 outputs for one c.
// ---------------------------------------------------------------------------
__global__ __launch_bounds__(512, 1)
void k2_wnew(const float* __restrict__ hid_ws,
             const float* __restrict__ mod_w2,
             const float* __restrict__ mod_b2,
             const float* __restrict__ Wg,
             const float* __restrict__ decay_logit,
             float* __restrict__ out)
{
    __shared__ float shid[512];        // [b][h] 8x64
    const int c    = blockIdx.x >> 3;
    const int part = blockIdx.x & 7;

    shid[TID] = hid_ws[((size_t)((TID >> 6) * 32 + c))*64 + (TID & 63)];
    __syncthreads();

    for (int idx = TID; idx < 516; idx += 512) {
        int o = part * 2064 + idx * 4;             // < 16512 always
        float4 acc0[8];
        {
            float4 bv = *(const float4*)(mod_b2 + (size_t)c*16512 + o);
            #pragma unroll
            for (int bb = 0; bb < 8; ++bb) acc0[bb] = bv;
        }
        const float* w2p = mod_w2 + (size_t)c*1056768 + o;
        #pragma unroll 8
        for (int hh = 0; hh < 64; ++hh) {
            float4 w4 = *(const float4*)(w2p + (size_t)hh*16512);
            #pragma unroll
            for (int bb = 0; bb < 8; ++bb) {
                float hv = shid[bb*64 + hh];
                acc0[bb].x += hv * w4.x; acc0[bb].y += hv * w4.y;
                acc0[bb].z += hv * w4.z; acc0[bb].w += hv * w4.w;
            }
        }
        if (o < 16384) {
            int n = o >> 7, m = o & 127;
            #pragma unroll
            for (int bb = 0; bb < 8; ++bb) {
                size_t wof = ((size_t)(bb*32 + c) << 14) + o;
                float4 Wv = *(const float4*)(Wg + wof);
                float4 r;
                r.x = Wv.x + acc0[bb].x;
                r.y = Wv.y + acc0[bb].y;
                r.z = Wv.z + acc0[bb].z;
                r.w = Wv.w + acc0[bb].w;
                if (n == m)     r.x = 0.f;
                else if (n == m+1) r.y = 0.f;
                else if (n == m+2) r.z = 0.f;
                else if (n == m+3) r.w = 0.f;
                *(float4*)(out + OUT_W + wof) = r;
            }
        } else {
            int m = o - 16384;
            #pragma unroll
            for (int bb = 0; bb < 8; ++bb) {
                size_t dof = (size_t)(bb*32 + c)*128 + m;
                float4 dl = *(const float4*)(decay_logit + dof);
                float4 r;
                r.x = dl.x + acc0[bb].x;
                r.y = dl.y + acc0[bb].y;
                r.z = dl.z + acc0[bb].z;
                r.w = dl.w + acc0[bb].w;
                *(float4*)(out + OUT_DEC + dof) = r;
            }
        }
    }
}

// ---------------------------------------------------------------------------
extern "C" void kernel_launch(void* const* d_in, const int* in_sizes, int n_in,
                              void* d_out, int out_size, void* d_ws, size_t ws_size,
                              hipStream_t stream)
{
    (void)in_sizes; (void)n_in; (void)out_size; (void)ws_size;
    const float* x              = (const float*)d_in[0];
    const float* h              = (const float*)d_in[1];
    const float* msg            = (const float*)d_in[2];
    const float* W              = (const float*)d_in[3];
    const float* decay_logit    = (const float*)d_in[4];
    const float* readout_drift  = (const float*)d_in[5];
    const float* s_mem_live     = (const float*)d_in[6];
    const float* s_mem_ema_fast = (const float*)d_in[7];
    const float* neuron_id      = (const float*)d_in[8];
    const float* state_w1       = (const float*)d_in[9];
    const float* state_b1       = (const float*)d_in[10];
    const float* state_w2       = (const float*)d_in[11];
    const float* state_b2       = (const float*)d_in[12];
    const float* msg_w1         = (const float*)d_in[13];
    const float* msg_b1         = (const float*)d_in[14];
    const float* msg_w2         = (const float*)d_in[15];
    const float* msg_b2         = (const float*)d_in[16];
    const float* inject_w       = (const float*)d_in[17];
    const float* inject_b       = (const float*)d_in[18];
    const float* mod_w1         = (const float*)d_in[19];
    const float* mod_b1         = (const float*)d_in[20];
    const float* mod_w2         = (const float*)d_in[21];
    const float* mod_b2         = (const float*)d_in[22];

    float* out = (float*)d_out;
    float* ws  = (float*)d_ws;   // hid: 256*64 floats = 64 KB

    hipLaunchKernelGGL(k1_cell, dim3(256), dim3(256), 0, stream,
                       x, h, msg, W, decay_logit, readout_drift,
                       s_mem_live, s_mem_ema_fast, neuron_id,
                       state_w1, state_b1, state_w2, state_b2,
                       msg_w1, msg_b1, msg_w2, msg_b2,
                       inject_w, inject_b, mod_w1, mod_b1,
                       out, ws);

    hipLaunchKernelGGL(k2_wnew, dim3(256), dim3(512), 0, stream,
                       ws, mod_w2, mod_b2, W, decay_logit, out);
}

// Round 3
// 312.352 us; speedup vs baseline: 1.1887x; 1.1887x over previous
//
#include <hip/hip_runtime.h>
#include <math.h>

// B=8, NC=32, N=128, D_N=64, ALPHA=4, HS=128, HM=128, HMOD=64
// MOD_IN=133, MOD_OUT=16512

#define OUT_RO   0u
#define OUT_H    16384u
#define OUT_MSG  2113536u
#define OUT_W    4210688u
#define OUT_DEC  8404992u

typedef __bf16 bf16x8 __attribute__((ext_vector_type(8)));
typedef float  f32x4  __attribute__((ext_vector_type(4)));

__device__ __forceinline__ unsigned short bf16_rne(float f){
    unsigned int u = __float_as_uint(f);
    u += 0x7fffu + ((u >> 16) & 1u);
    return (unsigned short)(u >> 16);
}
__device__ __forceinline__ float bf16_f(unsigned short s){
    return __uint_as_float(((unsigned int)s) << 16);
}
__device__ __forceinline__ float tanh_fast(float x){
    float e = __expf(2.f * x);
    return 1.f - 2.f / (e + 1.f);
}
__device__ __forceinline__ bf16x8 frag(const unsigned short* p, int row, int stride, int kbyte){
    return *(const bf16x8*)((const char*)(p + row * stride) + kbyte);
}
#define MFMA16(a, b, c) __builtin_amdgcn_mfma_f32_16x16x32_bf16(a, b, c, 0, 0, 0)

// ---------------------------------------------------------------------------
// Kernel 1: one block per (b,c) cell. bf16-MFMA matmul chain in LDS.
// 512 threads = 8 waves (2/SIMD). Wave grid: (wm 0..3) x (wn 0..1).
// Each wave: 2 m-tiles (rows wm*32 .. +31), 2 or 4 n-tiles.
// Fragment layouts (16x16x32): A lane: row=l&15, k=(l>>4)*8+j (k-contig);
// B lane: col=l&15 (stored as Bt[n][k], k-contig); D: col=l&15, row=(l>>4)*4+r.
// ---------------------------------------------------------------------------
__global__ __launch_bounds__(512)
void k1_cell(const float* __restrict__ x,
             const float* __restrict__ hg,
             const float* __restrict__ msgg,
             const float* __restrict__ Wg,
             const float* __restrict__ decay_logit,
             const float* __restrict__ readout_drift,
             const float* __restrict__ s_mem_live,
             const float* __restrict__ s_mem_ema_fast,
             const float* __restrict__ neuron_id,
             const float* __restrict__ state_w1,
             const float* __restrict__ state_b1,
             const float* __restrict__ state_w2,
             const float* __restrict__ state_b2,
             const float* __restrict__ msg_w1,
             const float* __restrict__ msg_b1,
             const float* __restrict__ msg_w2,
             const float* __restrict__ msg_b2,
             const float* __restrict__ inject_w,
             const float* __restrict__ inject_b,
             const float* __restrict__ mod_w1,
             const float* __restrict__ mod_b1,
             float* __restrict__ out,
             float* __restrict__ hid_ws)
{
    // bf16 tiles (padded strides: 136 for k-width 128, 72 for k-width 64)
    __shared__ __align__(16) unsigned short sW[128*136]; // W -> state_w1 -> hidden -> mh
    __shared__ __align__(16) unsigned short sM[64*136];  // msgT -> state_w2 -> msg_w2
    __shared__ __align__(16) unsigned short sR[128*72];  // received -> msg_w1
    __shared__ __align__(16) unsigned short sH[128*72];  // h -> h_new
    __shared__ __align__(16) float scrH[32*64];          // h_mean partials
    __shared__ __align__(16) float scrM[32*64];          // msg_mean partials
    __shared__ __align__(16) float s_inj[256];
    __shared__ float s_b1[128], s_mb1[128], s_b2[64], s_mb2[64];
    __shared__ float s_cell[64], s_dlog[128], s_dec[128];
    __shared__ float s_modin[136];
    __shared__ float s_wpart[8];

    const int tid  = (int)threadIdx.x;
    const int bid  = (int)blockIdx.x;      // b*32 + c
    const int b    = bid >> 5, c = bid & 31;
    const int wid  = tid >> 6, lane = tid & 63;
    const int q    = lane >> 4, r16 = lane & 15;
    const int wm   = wid >> 1, wn = wid & 1;
    const int ar   = wm*32 + r16;          // A row base (i adds 16)

    // ---------------- stage: W, msgT, h, scalars ----------------
    float wabs = 0.f;
    {
        const float4* src = (const float4*)(Wg + (size_t)bid * 16384);
        #pragma unroll
        for (int it = 0; it < 8; ++it) {
            int f4i = tid + it*512;                  // 128x128 -> 4096 f4
            float4 v = src[f4i];
            int n = f4i >> 5, k4 = (f4i & 31) << 2;
            ushort4 u;
            u.x = bf16_rne(v.x); u.y = bf16_rne(v.y);
            u.z = bf16_rne(v.z); u.w = bf16_rne(v.w);
            *(ushort4*)&sW[n*136 + k4] = u;
            wabs += fabsf(v.x)+fabsf(v.y)+fabsf(v.z)+fabsf(v.w);
        }
    }
    {   // msg (128x64) -> msgT (64 rows x 128 k)
        const float4* src = (const float4*)(msgg + (size_t)bid * 8192);
        #pragma unroll
        for (int it = 0; it < 4; ++it) {
            int f4i = tid + it*512;
            float4 v = src[f4i];
            int m = f4i >> 4, d4 = (f4i & 15) << 2;
            sM[(d4+0)*136 + m] = bf16_rne(v.x);
            sM[(d4+1)*136 + m] = bf16_rne(v.y);
            sM[(d4+2)*136 + m] = bf16_rne(v.z);
            sM[(d4+3)*136 + m] = bf16_rne(v.w);
        }
    }
    {   // h (128x64) row-major
        const float4* src = (const float4*)(hg + (size_t)bid * 8192);
        #pragma unroll
        for (int it = 0; it < 4; ++it) {
            int f4i = tid + it*512;
            float4 v = src[f4i];
            int n = f4i >> 4, d4 = (f4i & 15) << 2;
            ushort4 u;
            u.x = bf16_rne(v.x); u.y = bf16_rne(v.y);
            u.z = bf16_rne(v.z); u.w = bf16_rne(v.w);
            *(ushort4*)&sH[n*72 + d4] = u;
        }
    }
    if (tid < 128) {
        s_b1[tid]  = state_b1[tid];
        s_mb1[tid] = msg_b1[tid];
        float dl = decay_logit[(size_t)bid*128 + tid];
        s_dlog[tid] = dl;
        s_dec[tid]  = 1.f / (1.f + __expf(-dl));
    }
    if (tid < 64) {
        s_b2[tid]  = state_b2[tid];
        s_mb2[tid] = msg_b2[tid];
        s_cell[tid] = x[(size_t)b*2048 + c*64 + tid];
    }
    #pragma unroll
    for (int off = 32; off; off >>= 1) wabs += __shfl_down(wabs, off);
    if (lane == 0) s_wpart[wid] = wabs;

    __syncthreads();                                   // B0

    // inject (tid<256) + thread0 modin tail, overlapped with matmul1
    if (tid < 256) {
        int o = tid;
        float s = inject_b[(size_t)c*256 + o];
        const float4* iw = (const float4*)(inject_w + (size_t)c*16384 + (size_t)o*64);
        #pragma unroll
        for (int qq = 0; qq < 16; ++qq) {
            float4 w4 = iw[qq];
            float4 cl = *(const float4*)&s_cell[qq*4];
            s += w4.x*cl.x + w4.y*cl.y + w4.z*cl.z + w4.w*cl.w;
        }
        s_inj[o] = s;
    }
    if (tid == 0) {
        float ws_ = 0.f;
        #pragma unroll
        for (int i = 0; i < 8; ++i) ws_ += s_wpart[i];
        float ds = 0.f;
        for (int n = 0; n < 128; ++n) ds += s_dlog[n];
        s_modin[128] = ws_ * (1.f/16384.f);
        s_modin[129] = ds * (1.f/128.f);
        s_modin[130] = readout_drift[bid];
        s_modin[131] = s_mem_live[b];
        s_modin[132] = s_mem_ema_fast[b];
    }

    // ---------------- matmul1: received = W @ msg  (M128,N64,K128) --------
    f32x4 a1[2][2];
    #pragma unroll
    for (int i = 0; i < 2; ++i)
        #pragma unroll
        for (int j = 0; j < 2; ++j) a1[i][j] = (f32x4){0.f,0.f,0.f,0.f};
    #pragma unroll
    for (int ks = 0; ks < 4; ++ks) {
        int kb = ks*64 + q*16;
        bf16x8 A0 = frag(sW, ar,      136, kb);
        bf16x8 A1 = frag(sW, ar+16,   136, kb);
        bf16x8 B0 = frag(sM, wn*32 + r16,      136, kb);
        bf16x8 B1 = frag(sM, wn*32 + 16 + r16, 136, kb);
        a1[0][0] = MFMA16(A0, B0, a1[0][0]);
        a1[0][1] = MFMA16(A0, B1, a1[0][1]);
        a1[1][0] = MFMA16(A1, B0, a1[1][0]);
        a1[1][1] = MFMA16(A1, B1, a1[1][1]);
    }
    __syncthreads();                                   // B1 (sW/sM reads done; s_inj ready)

    // epilogue1: received (+inj on rows 0..3) -> bf16 sR
    #pragma unroll
    for (int i = 0; i < 2; ++i)
        #pragma unroll
        for (int j = 0; j < 2; ++j) {
            int colb = wn*32 + j*16 + r16;
            #pragma unroll
            for (int r = 0; r < 4; ++r) {
                int row = wm*32 + i*16 + q*4 + r;
                float v = a1[i][j][r];
                if (row < 4) { v += s_inj[row*64 + colb]; }
                sR[row*72 + colb] = bf16_rne(v);
            }
        }
    {   // stage state_w1 -> sW (128x128)
        const float4* src = (const float4*)state_w1;
        #pragma unroll
        for (int it = 0; it < 8; ++it) {
            int f4i = tid + it*512;
            float4 v = src[f4i];
            int n = f4i >> 5, k4 = (f4i & 31) << 2;
            ushort4 u;
            u.x = bf16_rne(v.x); u.y = bf16_rne(v.y);
            u.z = bf16_rne(v.z); u.w = bf16_rne(v.w);
            *(ushort4*)&sW[n*136 + k4] = u;
        }
    }
    {   // stage state_w2 -> sM (64x128)
        const float4* src = (const float4*)state_w2;
        #pragma unroll
        for (int it = 0; it < 4; ++it) {
            int f4i = tid + it*512;
            float4 v = src[f4i];
            int n = f4i >> 5, k4 = (f4i & 31) << 2;
            ushort4 u;
            u.x = bf16_rne(v.x); u.y = bf16_rne(v.y);
            u.z = bf16_rne(v.z); u.w = bf16_rne(v.w);
            *(ushort4*)&sM[n*136 + k4] = u;
        }
    }
    __syncthreads();                                   // B2

    // ---------------- matmul2: hidden = [recv|h] @ w1^T (M128,N128,K128) --
    f32x4 a2[2][4];
    #pragma unroll
    for (int i = 0; i < 2; ++i)
        #pragma unroll
        for (int j = 0; j < 4; ++j) a2[i][j] = (f32x4){0.f,0.f,0.f,0.f};
    #pragma unroll
    for (int ks = 0; ks < 2; ++ks) {                   // k 0..63: received
        int kb = ks*64 + q*16;
        bf16x8 A0 = frag(sR, ar,    72, kb);
        bf16x8 A1 = frag(sR, ar+16, 72, kb);
        #pragma unroll
        for (int j = 0; j < 4; ++j) {
            bf16x8 Bj = frag(sW, wn*64 + j*16 + r16, 136, kb);
            a2[0][j] = MFMA16(A0, Bj, a2[0][j]);
            a2[1][j] = MFMA16(A1, Bj, a2[1][j]);
        }
    }
    #pragma unroll
    for (int ks = 0; ks < 2; ++ks) {                   // k 64..127: h
        int kb = ks*64 + q*16;
        bf16x8 A0 = frag(sH, ar,    72, kb);
        bf16x8 A1 = frag(sH, ar+16, 72, kb);
        #pragma unroll
        for (int j = 0; j < 4; ++j) {
            bf16x8 Bj = frag(sW, wn*64 + j*16 + r16, 136, 128 + kb);
            a2[0][j] = MFMA16(A0, Bj, a2[0][j]);
            a2[1][j] = MFMA16(A1, Bj, a2[1][j]);
        }
    }
    __syncthreads();                                   // B3 (sW/sR reads done)

    // epilogue2: hidden = tanh(acc + b1) -> bf16 sW
    #pragma unroll
    for (int i = 0; i < 2; ++i)
        #pragma unroll
        for (int j = 0; j < 4; ++j) {
            int colb = wn*64 + j*16 + r16;
            float bb = s_b1[colb];
            #pragma unroll
            for (int r = 0; r < 4; ++r) {
                int row = wm*32 + i*16 + q*4 + r;
                sW[row*136 + colb] = bf16_rne(tanh_fast(a2[i][j][r] + bb));
            }
        }
    {   // stage msg_w1 -> sR (128x64)
        const float4* src = (const float4*)msg_w1;
        #pragma unroll
        for (int it = 0; it < 4; ++it) {
            int f4i = tid + it*512;
            float4 v = src[f4i];
            int n = f4i >> 4, d4 = (f4i & 15) << 2;
            ushort4 u;
            u.x = bf16_rne(v.x); u.y = bf16_rne(v.y);
            u.z = bf16_rne(v.z); u.w = bf16_rne(v.w);
            *(ushort4*)&sR[n*72 + d4] = u;
        }
    }
    __syncthreads();                                   // B4

    // ---------------- matmul3: cand = hidden @ w2^T (M128,N64,K128) -------
    f32x4 a3[2][2];
    #pragma unroll
    for (int i = 0; i < 2; ++i)
        #pragma unroll
        for (int j = 0; j < 2; ++j) a3[i][j] = (f32x4){0.f,0.f,0.f,0.f};
    #pragma unroll
    for (int ks = 0; ks < 4; ++ks) {
        int kb = ks*64 + q*16;
        bf16x8 A0 = frag(sW, ar,    136, kb);
        bf16x8 A1 = frag(sW, ar+16, 136, kb);
        bf16x8 B0 = frag(sM, wn*32 + r16,      136, kb);
        bf16x8 B1 = frag(sM, wn*32 + 16 + r16, 136, kb);
        a3[0][0] = MFMA16(A0, B0, a3[0][0]);
        a3[0][1] = MFMA16(A0, B1, a3[0][1]);
        a3[1][0] = MFMA16(A1, B0, a3[1][0]);
        a3[1][1] = MFMA16(A1, B1, a3[1][1]);
    }
    // epilogue3: h_new = dec*h + (1-dec)*tanh(acc+b2); global f32, sH bf16,
    // mean partials. (Lane-owned (row,col) slots: safe without barrier.)
    #pragma unroll
    for (int i = 0; i < 2; ++i)
        #pragma unroll
        for (int j = 0; j < 2; ++j) {
            int colb = wn*32 + j*16 + r16;
            float b2v = s_b2[colb];
            float psum = 0.f;
            #pragma unroll
            for (int r = 0; r < 4; ++r) {
                int row = wm*32 + i*16 + q*4 + r;
                float cand = tanh_fast(a3[i][j][r] + b2v);
                float hold = bf16_f(sH[row*72 + colb]);
                float dec  = s_dec[row];
                float hn   = dec*hold + (1.f - dec)*cand;
                out[OUT_H + (size_t)bid*8192 + row*64 + colb] = hn;
                sH[row*72 + colb] = bf16_rne(hn);
                psum += hn;
            }
            scrH[((wm*2 + i)*4 + q)*64 + colb] = psum;
        }
    __syncthreads();                                   // B5

    {   // stage msg_w2 -> sM (64x128)  (state_w2 readers done at B5)
        const float4* src = (const float4*)msg_w2;
        #pragma unroll
        for (int it = 0; it < 4; ++it) {
            int f4i = tid + it*512;
            float4 v = src[f4i];
            int n = f4i >> 5, k4 = (f4i & 31) << 2;
            ushort4 u;
            u.x = bf16_rne(v.x); u.y = bf16_rne(v.y);
            u.z = bf16_rne(v.z); u.w = bf16_rne(v.w);
            *(ushort4*)&sM[n*136 + k4] = u;
        }
    }

    // ---------------- matmul4: mh = h_new @ msg_w1^T (M128,N128,K64) ------
    f32x4 a4[2][4];
    #pragma unroll
    for (int i = 0; i < 2; ++i)
        #pragma unroll
        for (int j = 0; j < 4; ++j) a4[i][j] = (f32x4){0.f,0.f,0.f,0.f};
    #pragma unroll
    for (int ks = 0; ks < 2; ++ks) {
        int kb = ks*64 + q*16;
        bf16x8 A0 = frag(sH, ar,    72, kb);
        bf16x8 A1 = frag(sH, ar+16, 72, kb);
        #pragma unroll
        for (int j = 0; j < 4; ++j) {
            bf16x8 Bj = frag(sR, wn*64 + j*16 + r16, 72, kb);
            a4[0][j] = MFMA16(A0, Bj, a4[0][j]);
            a4[1][j] = MFMA16(A1, Bj, a4[1][j]);
        }
    }
    // epilogue4: mh = tanh(acc + mb1) -> bf16 sW (sW readers done at B5)
    #pragma unroll
    for (int i = 0; i < 2; ++i)
        #pragma unroll
        for (int j = 0; j < 4; ++j) {
            int colb = wn*64 + j*16 + r16;
            float bb = s_mb1[colb];
            #pragma unroll
            for (int r = 0; r < 4; ++r) {
                int row = wm*32 + i*16 + q*4 + r;
                sW[row*136 + colb] = bf16_rne(tanh_fast(a4[i][j][r] + bb));
            }
        }
    __syncthreads();                                   // B6

    // ---------------- matmul5: msg_new = mh @ msg_w2^T (M128,N64,K128) ----
    f32x4 a5[2][2];
    #pragma unroll
    for (int i = 0; i < 2; ++i)
        #pragma unroll
        for (int j = 0; j < 2; ++j) a5[i][j] = (f32x4){0.f,0.f,0.f,0.f};
    #pragma unroll
    for (int ks = 0; ks < 4; ++ks) {
        int kb = ks*64 + q*16;
        bf16x8 A0 = frag(sW, ar,    136, kb);
        bf16x8 A1 = frag(sW, ar+16, 136, kb);
        bf16x8 B0 = frag(sM, wn*32 + r16,      136, kb);
        bf16x8 B1 = frag(sM, wn*32 + 16 + r16, 136, kb);
        a5[0][0] = MFMA16(A0, B0, a5[0][0]);
        a5[0][1] = MFMA16(A0, B1, a5[0][1]);
        a5[1][0] = MFMA16(A1, B0, a5[1][0]);
        a5[1][1] = MFMA16(A1, B1, a5[1][1]);
    }
    // epilogue5: msg = tanh(acc+mb2) + neuron_id -> global f32; partials; readout
    #pragma unroll
    for (int i = 0; i < 2; ++i)
        #pragma unroll
        for (int j = 0; j < 2; ++j) {
            int colb = wn*32 + j*16 + r16;
            float mb = s_mb2[colb];
            float psum = 0.f;
            float rosum = 0.f;
            #pragma unroll
            for (int r = 0; r < 4; ++r) {
                int row = wm*32 + i*16 + q*4 + r;
                float nid = neuron_id[(size_t)c*8192 + row*64 + colb];
                float mn = tanh_fast(a5[i][j][r] + mb) + nid;
                out[OUT_MSG + (size_t)bid*8192 + row*64 + colb] = mn;
                psum += mn;
                rosum += mn;                            // only used when rows 4..7
            }
            scrM[((wm*2 + i)*4 + q)*64 + colb] = psum;
            if (wm == 0 && i == 0 && q == 1) {          // rows 4..7
                out[OUT_RO + (size_t)b*2048 + c*64 + colb] = 0.5f * rosum;
            }
        }
    __syncthreads();                                   // B7

    if (tid < 64) {
        float hm = 0.f, mm = 0.f;
        #pragma unroll
        for (int g = 0; g < 32; ++g) { hm += scrH[g*64 + tid]; mm += scrM[g*64 + tid]; }
        s_modin[tid]      = hm * (1.f/128.f);
        s_modin[64 + tid] = mm * (1.f/128.f);
    }
    __syncthreads();                                   // B8

    // mod MLP layer 1: hid = tanh(modin(133) @ mod_w1[c] + mod_b1)
    if (tid < 64) {
        int hh = tid;
        float a = mod_b1[(size_t)c*64 + hh];
        const float* w1p = mod_w1 + (size_t)c*8512 + hh;   // (133,64)
        #pragma unroll 7
        for (int i = 0; i < 133; ++i)
            a += s_modin[i] * w1p[(size_t)i*64];
        hid_ws[(size_t)bid*64 + hh] = tanh_fast(a);
    }
}

// ---------------------------------------------------------------------------
// Kernel 2: outm = hid @ mod_w2 + mod_b2; W_new (blocks 0..511, exact fit,
// no tail) and decay_new (blocks 512..515).
// ---------------------------------------------------------------------------
__global__ __launch_bounds__(256)
void k2_wnew(const float* __restrict__ hid_ws,
             const float* __restrict__ mod_w2,
             const float* __restrict__ mod_b2,
             const float* __restrict__ Wg,
             const float* __restrict__ decay_logit,
             float* __restrict__ out)
{
    __shared__ float shid[4096];
    const int tid = (int)threadIdx.x;

    if ((int)blockIdx.x < 512) {
        const int c = (int)blockIdx.x >> 4, part = (int)blockIdx.x & 15;
        shid[tid]       = hid_ws[(size_t)((tid>>6)*32 + c)*64 + (tid&63)];
        shid[tid + 256] = hid_ws[(size_t)(((tid>>6)+4)*32 + c)*64 + (tid&63)];
        __syncthreads();

        const int o = (part*256 + tid) * 4;            // 0..16380, W region only
        float4 acc[8];
        {
            float4 bv = *(const float4*)(mod_b2 + (size_t)c*16512 + o);
            #pragma unroll
            for (int bb = 0; bb < 8; ++bb) acc[bb] = bv;
        }
        const float* w2p = mod_w2 + (size_t)c*1056768 + o;
        #pragma unroll 16
        for (int hh = 0; hh < 64; ++hh) {
            float4 w4 = *(const float4*)(w2p + (size_t)hh*16512);
            #pragma unroll
            for (int bb = 0; bb < 8; ++bb) {
                float hv = shid[bb*64 + hh];
                acc[bb].x += hv * w4.x; acc[bb].y += hv * w4.y;
                acc[bb].z += hv * w4.z; acc[bb].w += hv * w4.w;
            }
        }
        const int n = o >> 7, m = o & 127;
        #pragma unroll
        for (int bb = 0; bb < 8; ++bb) {
            size_t wof = ((size_t)(bb*32 + c) << 14) + o;
            float4 Wv = *(const float4*)(Wg + wof);
            float4 r;
            r.x = Wv.x + acc[bb].x;
            r.y = Wv.y + acc[bb].y;
            r.z = Wv.z + acc[bb].z;
            r.w = Wv.w + acc[bb].w;
            if (n == m)        r.x = 0.f;
            else if (n == m+1) r.y = 0.f;
            else if (n == m+2) r.z = 0.f;
            else if (n == m+3) r.w = 0.f;
            *(float4*)(out + OUT_W + wof) = r;
        }
    } else {
        // decay tail: 4 blocks x 256 threads; 8 c's per block, 32 f4 per c
        const int base_c = ((int)blockIdx.x - 512) * 8;
        #pragma unroll
        for (int it = 0; it < 16; ++it) {
            int idx = tid + it*256;                    // 0..4095
            int c_l = idx >> 9, rem = idx & 511;
            int bb = rem >> 6, h = rem & 63;
            shid[idx] = hid_ws[(size_t)(bb*32 + base_c + c_l)*64 + h];
        }
        __syncthreads();

        const int c_l = tid >> 5;                      // 0..7
        const int c   = base_c + c_l;
        const int m4  = (tid & 31) * 4;                // 0..124
        const int o   = 16384 + m4;
        float4 acc[8];
        {
            float4 bv = *(const float4*)(mod_b2 + (size_t)c*16512 + o);
            #pragma unroll
            for (int bb = 0; bb < 8; ++bb) acc[bb] = bv;
        }
        const float* w2p = mod_w2 + (size_t)c*1056768 + o;
        #pragma unroll 16
        for (int hh = 0; hh < 64; ++hh) {
            float4 w4 = *(const float4*)(w2p + (size_t)hh*16512);
            #pragma unroll
            for (int bb = 0; bb < 8; ++bb) {
                float hv = shid[c_l*512 + bb*64 + hh];
                acc[bb].x += hv * w4.x; acc[bb].y += hv * w4.y;
                acc[bb].z += hv * w4.z; acc[bb].w += hv * w4.w;
            }
        }
        #pragma unroll
        for (int bb = 0; bb < 8; ++bb) {
            size_t dof = (size_t)(bb*32 + c)*128 + m4;
            float4 dl = *(const float4*)(decay_logit + dof);
            float4 r;
            r.x = dl.x + acc[bb].x;
            r.y = dl.y + acc[bb].y;
            r.z = dl.z + acc[bb].z;
            r.w = dl.w + acc[bb].w;
            *(float4*)(out + OUT_DEC + dof) = r;
        }
    }
}

// ---------------------------------------------------------------------------
extern "C" void kernel_launch(void* const* d_in, const int* in_sizes, int n_in,
                              void* d_out, int out_size, void* d_ws, size_t ws_size,
                              hipStream_t stream)
{
    (void)in_sizes; (void)n_in; (void)out_size; (void)ws_size;
    const float* x              = (const float*)d_in[0];
    const float* h              = (const float*)d_in[1];
    const float* msg            = (const float*)d_in[2];
    const float* W              = (const float*)d_in[3];
    const float* decay_logit    = (const float*)d_in[4];
    const float* readout_drift  = (const float*)d_in[5];
    const float* s_mem_live     = (const float*)d_in[6];
    const float* s_mem_ema_fast = (const float*)d_in[7];
    const float* neuron_id      = (const float*)d_in[8];
    const float* state_w1       = (const float*)d_in[9];
    const float* state_b1       = (const float*)d_in[10];
    const float* state_w2       = (const float*)d_in[11];
    const float* state_b2       = (const float*)d_in[12];
    const float* msg_w1         = (const float*)d_in[13];
    const float* msg_b1         = (const float*)d_in[14];
    const float* msg_w2         = (const float*)d_in[15];
    const float* msg_b2         = (const float*)d_in[16];
    const float* inject_w       = (const float*)d_in[17];
    const float* inject_b       = (const float*)d_in[18];
    const float* mod_w1         = (const float*)d_in[19];
    const float* mod_b1         = (const float*)d_in[20];
    const float* mod_w2         = (const float*)d_in[21];
    const float* mod_b2         = (const float*)d_in[22];

    float* out = (float*)d_out;
    float* ws  = (float*)d_ws;   // hid: 256*64 floats

    hipLaunchKernelGGL(k1_cell, dim3(256), dim3(512), 0, stream,
                       x, h, msg, W, decay_logit, readout_drift,
                       s_mem_live, s_mem_ema_fast, neuron_id,
                       state_w1, state_b1, state_w2, state_b2,
                       msg_w1, msg_b1, msg_w2, msg_b2,
                       inject_w, inject_b, mod_w1, mod_b1,
                       out, ws);

    hipLaunchKernelGGL(k2_wnew, dim3(516), dim3(256), 0, stream,
                       ws, mod_w2, mod_b2, W, decay_logit, out);
}